// Round 7
// baseline (340.736 us; speedup 1.0000x reference)
//
#include <hip/hip_runtime.h>
#include <math.h>

#define NN 10000      // nodes
#define NE 160000     // edges
#define C  32         // FEAT == EMB == HID == 32
#define ED 9          // edge feature dim
#define EAP 12        // padded edge-attr stride (16B-aligned float4 loads)

typedef __attribute__((ext_vector_type(8))) short short8v;   // 8 bf16 (4 VGPR)
typedef __attribute__((ext_vector_type(4))) float float4v;

__device__ inline unsigned short f2bf(float f) {        // fp32 -> bf16 RNE
    unsigned int u = __float_as_uint(f);
    return (unsigned short)((u + 0x7fffu + ((u >> 16) & 1u)) >> 16);
}

// ---------------------------------------------------------------------------
// prep_kernel: blocks [0,40) zero the atomic region (cnt/cursors/counter);
//              [40,168) transpose w1b; [168,296) transpose w2b.
// wbT[o*1024 + k*32 + i] = wb[k*1024 + i*32 + o]
// ---------------------------------------------------------------------------
#define ZQ 10016      // uint4s in zero region (40064 ints)
__global__ __launch_bounds__(256) void prep_kernel(uint4* __restrict__ zreg,
                                                   const float* __restrict__ w1b,
                                                   const float* __restrict__ w2b,
                                                   float* __restrict__ wbT1,
                                                   float* __restrict__ wbT2) {
    const int b = blockIdx.x, tid = threadIdx.x;
    if (b < 40) {
        const int i = b * 256 + tid;
        if (i < ZQ) zreg[i] = uint4{0u, 0u, 0u, 0u};
    } else if (b < 168) {
        const int idx = (b - 40) * 256 + tid;             // 0..32767
        const int i = idx & 31, k = (idx >> 5) & 31, o = idx >> 10;
        wbT1[idx] = w1b[k * (C * C) + i * C + o];
    } else {
        const int idx = (b - 168) * 256 + tid;
        const int i = idx & 31, k = (idx >> 5) & 31, o = idx >> 10;
        wbT2[idx] = w2b[k * (C * C) + i * C + o];
    }
}

// ---------------------------------------------------------------------------
// hist_kernel: out-degree (src) and in-degree (dst) histograms
// ---------------------------------------------------------------------------
__global__ __launch_bounds__(256) void hist_kernel(const int* __restrict__ ei,
                                                   int* __restrict__ cnt_src,
                                                   int* __restrict__ cnt_dst) {
    const int e = blockIdx.x * 256 + threadIdx.x;
    if (e < NE) {
        atomicAdd(&cnt_src[ei[e]], 1);
        atomicAdd(&cnt_dst[ei[NE + e]], 1);
    }
}

// ---------------------------------------------------------------------------
// scan2_kernel: block 0: offs = exscan(cnt_src); block 1: doffs = exscan(cnt_dst)
// wave-shuffle scan, 2 barriers.
// ---------------------------------------------------------------------------
__global__ __launch_bounds__(1024) void scan2_kernel(const int* __restrict__ cnt_src,
                                                     const int* __restrict__ cnt_dst,
                                                     int* __restrict__ offs,
                                                     int* __restrict__ doffs) {
    const int* cnt = blockIdx.x ? cnt_dst : cnt_src;
    int* out       = blockIdx.x ? doffs   : offs;
    __shared__ int wtot[16];
    const int t = threadIdx.x;
    const int lane = t & 63, wid = t >> 6;
    const int base = t * 10;
    int loc[10];
    int s = 0;
#pragma unroll
    for (int j = 0; j < 10; ++j) {
        int v = (base + j < NN) ? cnt[base + j] : 0;
        loc[j] = s;
        s += v;
    }
    int inc = s;
    for (int d = 1; d < 64; d <<= 1) {
        int v = __shfl_up(inc, d, 64);
        if (lane >= d) inc += v;
    }
    if (lane == 63) wtot[wid] = inc;
    __syncthreads();
    if (t < 16) {
        int w = wtot[t];
        for (int d = 1; d < 16; d <<= 1) {
            int v = __shfl_up(w, d, 64);
            if (t >= d) w += v;
        }
        wtot[t] = w;
    }
    __syncthreads();
    const int excl = inc - s + (wid ? wtot[wid - 1] : 0);
#pragma unroll
    for (int j = 0; j < 10; ++j)
        if (base + j < NN) out[base + j] = excl + loc[j];
    if (t == 1023) out[NN] = wtot[15];
}

// ---------------------------------------------------------------------------
// u_body: U_T[n][o][k] = f2bf(sum_i xin[n,i]*wb[k,i*32+o]); xb[n][o] likewise.
// vb in [0,2500): (16 nodes) x (8-of-32 o cols).
// ---------------------------------------------------------------------------
__device__ __forceinline__ void u_body(int vb, int tid, float* __restrict__ xs,
                                       const float* __restrict__ xin,
                                       const float* __restrict__ wbT,
                                       const float* __restrict__ bb,
                                       unsigned short* __restrict__ UT,
                                       float* __restrict__ xb) {
    const int nb = (vb >> 2) * 16;
    const int o0 = (vb & 3) * 8;
    for (int t = tid; t < 16 * C; t += 256) xs[t] = xin[nb * C + t];
    __syncthreads();

    const int op = tid >> 5, k = tid & 31, o = o0 + op;
    float4v wv[8];
    const float* wp = wbT + ((size_t)o * C + k) * C;
#pragma unroll
    for (int i4 = 0; i4 < 8; ++i4)
        wv[i4] = *reinterpret_cast<const float4v*>(wp + i4 * 4);

#pragma unroll
    for (int n = 0; n < 16; ++n) {
        float acc = 0.f;
#pragma unroll
        for (int i4 = 0; i4 < 8; ++i4) {
            const float4v xv = *reinterpret_cast<const float4v*>(&xs[n * C + i4 * 4]);
            acc += xv.x * wv[i4].x + xv.y * wv[i4].y + xv.z * wv[i4].z + xv.w * wv[i4].w;
        }
        UT[(size_t)(nb + n) * (C * C) + o * C + k] = f2bf(acc);
    }
    if (o0 == 0) {
#pragma unroll
        for (int t = 0; t < 2; ++t) {
            const int idx = t * 256 + tid;
            const int n = idx >> 5, oo = idx & 31;
            float acc = 0.f;
#pragma unroll
            for (int i = 0; i < C; ++i) acc += xs[n * C + i] * bb[i * C + oo];
            xb[(size_t)(nb + n) * C + oo] = acc;
        }
    }
}

// ---------------------------------------------------------------------------
// mid_kernel: blocks [0,625): scatter (CSR payload + dst-rank pd);
//             blocks [625,3125): u_body for conv1.
// ---------------------------------------------------------------------------
__global__ __launch_bounds__(256) void mid_kernel(const int* __restrict__ ei,
                                                  const float* __restrict__ ea,
                                                  const int* __restrict__ offs,
                                                  const int* __restrict__ doffs,
                                                  int* __restrict__ cur_src,
                                                  int* __restrict__ cur_dst,
                                                  int* __restrict__ pd,
                                                  float* __restrict__ ea_s,
                                                  const float* __restrict__ xin,
                                                  const float* __restrict__ wbT,
                                                  const float* __restrict__ bb,
                                                  unsigned short* __restrict__ UT,
                                                  float* __restrict__ xb) {
    __shared__ float xs[16 * C];
    const int b = blockIdx.x, tid = threadIdx.x;
    if (b < 625) {
        const int e = b * 256 + tid;
        if (e < NE) {
            const int sn  = ei[e];
            const int dn  = ei[NE + e];
            const int pos = offs[sn]  + atomicAdd(&cur_src[sn], 1);
            const int dpo = doffs[dn] + atomicAdd(&cur_dst[dn], 1);
            pd[pos] = dpo;
#pragma unroll
            for (int j = 0; j < ED; ++j)
                ea_s[(size_t)pos * EAP + j] = ea[(size_t)e * ED + j];
        }
    } else {
        u_body(b - 625, tid, xs, xin, wbT, bb, UT, xb);
    }
}

// u_gemm2 standalone (conv2, input h1)
__global__ __launch_bounds__(256) void u_gemm2(const float* __restrict__ xin,
                                               const float* __restrict__ wbT,
                                               const float* __restrict__ bb,
                                               unsigned short* __restrict__ UT,
                                               float* __restrict__ xb) {
    __shared__ float xs[16 * C];
    u_body(blockIdx.x, threadIdx.x, xs, xin, wbT, bb, UT, xb);
}

// ---------------------------------------------------------------------------
// edge5_kernel: one wave per src; 16-edge groups via MFMA; messages stored
// (no atomics) at dst-sorted rank pd[p]: msg[pd[p]][o].
// ---------------------------------------------------------------------------
__global__ __launch_bounds__(256) void edge5_kernel(const int* __restrict__ offs,
                                                    const int* __restrict__ pd,
                                                    const float* __restrict__ ea_s,
                                                    const float* __restrict__ wa,
                                                    const float* __restrict__ ba,
                                                    const unsigned short* __restrict__ UT,
                                                    const float* __restrict__ xb,
                                                    float* __restrict__ msg) {
    __shared__ float was[ED * C];
    __shared__ float bas[C];
    const int tid = threadIdx.x;
    for (int t = tid; t < ED * C; t += 256) was[t] = wa[t];
    if (tid < C) bas[tid] = ba[tid];
    __syncthreads();

    const int w  = tid >> 6;
    const int l  = tid & 63;
    const int s  = blockIdx.x * 4 + w;     // 2500*4 == 10000
    const int q  = l >> 4;                 // k-block 0..3
    const int el = l & 15;                 // edge row / output col

    const int e0 = offs[s], e1 = offs[s + 1];
    if (e0 == e1) return;

    const unsigned short* up = UT + (size_t)s * (C * C);
    const short8v B1 = *reinterpret_cast<const short8v*>(up + el * C + q * 8);
    const short8v B2 = *reinterpret_cast<const short8v*>(up + (el + 16) * C + q * 8);
    const float c1 = xb[s * C + el];
    const float c2 = xb[s * C + el + 16];
    const float4v C1 = {c1, c1, c1, c1};
    const float4v C2 = {c2, c2, c2, c2};
    float hb[8];
#pragma unroll
    for (int i = 0; i < 8; ++i) hb[i] = bas[q * 8 + i];

    for (int pb = e0; pb < e1; pb += 16) {
        const int p  = pb + el;
        const int pc = (p < e1) ? p : e0;          // clamp (masked at store)
        const float* eap = ea_s + (size_t)pc * EAP;
        const float4v ea0 = *reinterpret_cast<const float4v*>(eap);
        const float4v ea1 = *reinterpret_cast<const float4v*>(eap + 4);
        const float   ea8 = eap[8];

        float h[8];
#pragma unroll
        for (int i = 0; i < 8; ++i) h[i] = hb[i];
#pragma unroll
        for (int j = 0; j < ED; ++j) {
            const float ev = (j == 0) ? ea0.x : (j == 1) ? ea0.y : (j == 2) ? ea0.z
                           : (j == 3) ? ea0.w : (j == 4) ? ea1.x : (j == 5) ? ea1.y
                           : (j == 6) ? ea1.z : (j == 7) ? ea1.w : ea8;
            const float4v w0 = *reinterpret_cast<const float4v*>(&was[j * C + q * 8]);
            const float4v w1 = *reinterpret_cast<const float4v*>(&was[j * C + q * 8 + 4]);
            h[0] += ev * w0.x; h[1] += ev * w0.y; h[2] += ev * w0.z; h[3] += ev * w0.w;
            h[4] += ev * w1.x; h[5] += ev * w1.y; h[6] += ev * w1.z; h[7] += ev * w1.w;
        }
        union { int u[4]; short8v v; } A;
#pragma unroll
        for (int v = 0; v < 4; ++v) {
            const unsigned lo = f2bf(fmaxf(h[2 * v], 0.f));
            const unsigned hi = f2bf(fmaxf(h[2 * v + 1], 0.f));
            A.u[v] = (int)(lo | (hi << 16));
        }
        const float4v d1 = __builtin_amdgcn_mfma_f32_16x16x32_bf16(A.v, B1, C1, 0, 0, 0);
        const float4v d2 = __builtin_amdgcn_mfma_f32_16x16x32_bf16(A.v, B2, C2, 0, 0, 0);
#pragma unroll
        for (int r = 0; r < 4; ++r) {
            const int pe = pb + q * 4 + r;          // D row = (l>>4)*4 + r
            if (pe < e1) {
                const int mr = pd[pe];
                msg[(size_t)mr * C + el]      = d1[r];
                msg[(size_t)mr * C + el + 16] = d2[r];
            }
        }
    }
}

// ---------------------------------------------------------------------------
// nodeagg1: one wave per dst; segmented mean over msg rows + node update.
//   h1[d,o] = relu(mean + x[d,:]@root1[:,o] + bias1[o])
// ---------------------------------------------------------------------------
__global__ __launch_bounds__(256) void nodeagg1_kernel(const int* __restrict__ doffs,
                                                       const float* __restrict__ msg,
                                                       const float* __restrict__ xin,
                                                       const float* __restrict__ root,
                                                       const float* __restrict__ bias,
                                                       float* __restrict__ h1out) {
    __shared__ float rs[C * C];
    __shared__ float bs[C];
    __shared__ float xls[4][C];
    const int tid = threadIdx.x;
    for (int t = tid; t < C * C; t += 256) rs[t] = root[t];
    if (tid < C) bs[tid] = bias[tid];
    __syncthreads();

    const int w = tid >> 6, lane = tid & 63;
    const int half = lane >> 5, o = lane & 31;
    const int d = blockIdx.x * 4 + w;
    const int e0 = doffs[d], e1 = doffs[d + 1];

    float acc = 0.f;
    for (int p = e0 + half; p < e1; p += 2) acc += msg[(size_t)p * C + o];
    acc += __shfl_down(acc, 32, 64);                 // lanes 0-31 hold full sum
    if (lane < 32) xls[w][o] = xin[(size_t)d * C + o];  // wave-local, DS in-order
    if (lane < 32) {
        const float cn = fmaxf((float)(e1 - e0), 1.f);
        float a = bs[o] + acc / cn;
#pragma unroll
        for (int i = 0; i < C; ++i) a += xls[w][i] * rs[i * C + o];
        h1out[(size_t)d * C + o] = fmaxf(a, 0.f);
    }
}

// ---------------------------------------------------------------------------
// nodeagg2_out: one wave per dst; h2 in-register -> score; last block does
// logsumexp + final output write.
// ---------------------------------------------------------------------------
__global__ __launch_bounds__(256) void nodeagg2_out(const int* __restrict__ doffs,
                                                    const float* __restrict__ msg,
                                                    const float* __restrict__ h1,
                                                    const float* __restrict__ root,
                                                    const float* __restrict__ bias,
                                                    const float* __restrict__ emb,
                                                    const int* __restrict__ signal,
                                                    float* __restrict__ scores,
                                                    int* __restrict__ counter,
                                                    float* __restrict__ out) {
    __shared__ float rs[C * C];
    __shared__ float bs[C];
    __shared__ float sig[C];
    __shared__ float xls[4][C];
    __shared__ int   is_last;
    __shared__ float sm[4];
    const int tid = threadIdx.x;
    for (int t = tid; t < C * C; t += 256) rs[t] = root[t];
    if (tid < C) {
        bs[tid]  = bias[tid];
        sig[tid] = emb[(size_t)signal[0] * C + tid];
    }
    __syncthreads();

    const int w = tid >> 6, lane = tid & 63;
    const int half = lane >> 5, o = lane & 31;
    const int d = blockIdx.x * 4 + w;
    const int e0 = doffs[d], e1 = doffs[d + 1];

    float acc = 0.f;
    for (int p = e0 + half; p < e1; p += 2) acc += msg[(size_t)p * C + o];
    acc += __shfl_down(acc, 32, 64);
    if (lane < 32) xls[w][o] = h1[(size_t)d * C + o];
    if (lane < 32) {
        const float cn = fmaxf((float)(e1 - e0), 1.f);
        float a = bs[o] + acc / cn;
#pragma unroll
        for (int i = 0; i < C; ++i) a += xls[w][i] * rs[i * C + o];
        float val = fmaxf(a, 0.f) * sig[o];
#pragma unroll
        for (int off = 16; off; off >>= 1) val += __shfl_xor(val, off, 32);
        if (o == 0) scores[d] = val;
    }

    // ---- last-block logsumexp + output ----
    __threadfence();
    if (tid == 0) is_last = (atomicAdd(counter, 1) == gridDim.x - 1);
    __syncthreads();
    if (!is_last) return;
    __threadfence();

    float m = -INFINITY;
    for (int n = tid; n < NN; n += 256) m = fmaxf(m, scores[n]);
#pragma unroll
    for (int off = 32; off; off >>= 1) m = fmaxf(m, __shfl_down(m, off, 64));
    if (lane == 0) sm[w] = m;
    __syncthreads();
    const float gmax = fmaxf(fmaxf(sm[0], sm[1]), fmaxf(sm[2], sm[3]));
    float s = 0.f;
    for (int n = tid; n < NN; n += 256) s += expf(scores[n] - gmax);
#pragma unroll
    for (int off = 32; off; off >>= 1) s += __shfl_down(s, off, 64);
    if (lane == 0) sm[w] = s;
    __syncthreads();
    const float sub = gmax + logf(sm[0] + sm[1] + sm[2] + sm[3]);
    for (int n = tid; n < NN; n += 256) out[n] = scores[n] - sub;
}

// ---------------------------------------------------------------------------
extern "C" void kernel_launch(void* const* d_in, const int* in_sizes, int n_in,
                              void* d_out, int out_size, void* d_ws, size_t ws_size,
                              hipStream_t stream) {
    const int*   signal = (const int*)d_in[0];
    const float* x      = (const float*)d_in[1];
    const int*   ei     = (const int*)d_in[2];
    const float* ea     = (const float*)d_in[3];
    const float* w1a    = (const float*)d_in[4];
    const float* b1a    = (const float*)d_in[5];
    const float* w1b    = (const float*)d_in[6];
    const float* b1b    = (const float*)d_in[7];
    const float* root1  = (const float*)d_in[8];
    const float* bias1  = (const float*)d_in[9];
    const float* w2a    = (const float*)d_in[10];
    const float* b2a    = (const float*)d_in[11];
    const float* w2b    = (const float*)d_in[12];
    const float* b2b    = (const float*)d_in[13];
    const float* root2  = (const float*)d_in[14];
    const float* bias2  = (const float*)d_in[15];
    const float* emb    = (const float*)d_in[16];

    // ---- workspace layout (float words; ws_size = 256 MiB, we use ~52 MB) ----
    float* ws = (float*)d_ws;
    unsigned short* UT = (unsigned short*)ws;         // 5,120,000 words (20.5 MB)
    float* msg     = ws + 5120000;                    // 5,120,000 (20.5 MB)
    float* xb      = msg + 5120000;                   // 320,000
    float* h1      = xb + 320000;                     // 320,000
    float* ea_s    = h1 + 320000;                     // 1,920,000
    float* wbT1    = ea_s + 1920000;                  // 32,768
    float* wbT2    = wbT1 + 32768;                    // 32,768
    float* scores  = wbT2 + 32768;                    // 10,000
    int*   offs    = (int*)(scores + 10000);          // 10,016
    int*   doffs   = offs + 10016;                    // 10,016
    int*   pd      = doffs + 10016;                   // 160,000
    // ---- zero region (40,064 ints == 10,016 uint4, zeroed by prep) ----
    int*   cnt_src = pd + 160000;                     // 10,000
    int*   cnt_dst = cnt_src + NN;                    // 10,000
    int*   cur_src = cnt_dst + NN;                    // 10,000
    int*   cur_dst = cur_src + NN;                    // 10,000
    int*   counter = cur_dst + NN;                    // 64

    // 1: zero + both wb transposes
    prep_kernel<<<296, 256, 0, stream>>>((uint4*)cnt_src, w1b, w2b, wbT1, wbT2);
    // 2: degree histograms
    hist_kernel<<<(NE + 255) / 256, 256, 0, stream>>>(ei, cnt_src, cnt_dst);
    // 3: both prefix scans
    scan2_kernel<<<2, 1024, 0, stream>>>(cnt_src, cnt_dst, offs, doffs);
    // 4: scatter (CSR payload + dst ranks)  ||  conv1 U/xb
    mid_kernel<<<3125, 256, 0, stream>>>(ei, ea, offs, doffs, cur_src, cur_dst,
                                         pd, ea_s, x, wbT1, b1b, UT, xb);
    // 5: conv1 edge MFMA -> msg (dst-sorted, no atomics)
    edge5_kernel<<<2500, 256, 0, stream>>>(offs, pd, ea_s, w1a, b1a, UT, xb, msg);
    // 6: conv1 segmented mean + node update -> h1
    nodeagg1_kernel<<<2500, 256, 0, stream>>>(doffs, msg, x, root1, bias1, h1);
    // 7: conv2 U/xb from h1
    u_gemm2<<<2500, 256, 0, stream>>>(h1, wbT2, b2b, UT, xb);
    // 8: conv2 edge MFMA -> msg
    edge5_kernel<<<2500, 256, 0, stream>>>(offs, pd, ea_s, w2a, b2a, UT, xb, msg);
    // 9: conv2 aggregation + score + last-block logsumexp + output
    nodeagg2_out<<<2500, 256, 0, stream>>>(doffs, msg, h1, root2, bias2,
                                           emb, signal, scores, counter, (float*)d_out);
}

// Round 8
// 157.061 us; speedup vs baseline: 2.1694x; 2.1694x over previous
//
#include <hip/hip_runtime.h>
#include <math.h>

#define NN 10000      // nodes
#define NE 160000     // edges
#define C  32         // FEAT == EMB == HID == 32
#define ED 9          // edge feature dim
#define EAP 12        // padded edge-attr stride (16B-aligned float4 loads)

typedef __attribute__((ext_vector_type(8))) short short8v;   // 8 bf16 (4 VGPR)
typedef __attribute__((ext_vector_type(4))) float float4v;

__device__ inline unsigned short f2bf(float f) {        // fp32 -> bf16 RNE
    unsigned int u = __float_as_uint(f);
    return (unsigned short)((u + 0x7fffu + ((u >> 16) & 1u)) >> 16);
}

// ---------------------------------------------------------------------------
// prep_kernel: blocks [0,40) zero the atomic region (cnt/cursors);
//              [40,168) transpose w1b; [168,296) transpose w2b.
// wbT[o*1024 + k*32 + i] = wb[k*1024 + i*32 + o]
// ---------------------------------------------------------------------------
#define ZQ 10016      // uint4s in zero region (40064 ints)
__global__ __launch_bounds__(256) void prep_kernel(uint4* __restrict__ zreg,
                                                   const float* __restrict__ w1b,
                                                   const float* __restrict__ w2b,
                                                   float* __restrict__ wbT1,
                                                   float* __restrict__ wbT2) {
    const int b = blockIdx.x, tid = threadIdx.x;
    if (b < 40) {
        const int i = b * 256 + tid;
        if (i < ZQ) zreg[i] = uint4{0u, 0u, 0u, 0u};
    } else if (b < 168) {
        const int idx = (b - 40) * 256 + tid;             // 0..32767
        const int i = idx & 31, k = (idx >> 5) & 31, o = idx >> 10;
        wbT1[idx] = w1b[k * (C * C) + i * C + o];
    } else {
        const int idx = (b - 168) * 256 + tid;
        const int i = idx & 31, k = (idx >> 5) & 31, o = idx >> 10;
        wbT2[idx] = w2b[k * (C * C) + i * C + o];
    }
}

// ---------------------------------------------------------------------------
// hist_kernel: out-degree (src) and in-degree (dst) histograms
// ---------------------------------------------------------------------------
__global__ __launch_bounds__(256) void hist_kernel(const int* __restrict__ ei,
                                                   int* __restrict__ cnt_src,
                                                   int* __restrict__ cnt_dst) {
    const int e = blockIdx.x * 256 + threadIdx.x;
    if (e < NE) {
        atomicAdd(&cnt_src[ei[e]], 1);
        atomicAdd(&cnt_dst[ei[NE + e]], 1);
    }
}

// ---------------------------------------------------------------------------
// scan2_kernel: block 0: offs = exscan(cnt_src); block 1: doffs = exscan(cnt_dst)
// wave-shuffle scan, 2 barriers.
// ---------------------------------------------------------------------------
__global__ __launch_bounds__(1024) void scan2_kernel(const int* __restrict__ cnt_src,
                                                     const int* __restrict__ cnt_dst,
                                                     int* __restrict__ offs,
                                                     int* __restrict__ doffs) {
    const int* cnt = blockIdx.x ? cnt_dst : cnt_src;
    int* out       = blockIdx.x ? doffs   : offs;
    __shared__ int wtot[16];
    const int t = threadIdx.x;
    const int lane = t & 63, wid = t >> 6;
    const int base = t * 10;
    int loc[10];
    int s = 0;
#pragma unroll
    for (int j = 0; j < 10; ++j) {
        int v = (base + j < NN) ? cnt[base + j] : 0;
        loc[j] = s;
        s += v;
    }
    int inc = s;
    for (int d = 1; d < 64; d <<= 1) {
        int v = __shfl_up(inc, d, 64);
        if (lane >= d) inc += v;
    }
    if (lane == 63) wtot[wid] = inc;
    __syncthreads();
    if (t < 16) {
        int w = wtot[t];
        for (int d = 1; d < 16; d <<= 1) {
            int v = __shfl_up(w, d, 64);
            if (t >= d) w += v;
        }
        wtot[t] = w;
    }
    __syncthreads();
    const int excl = inc - s + (wid ? wtot[wid - 1] : 0);
#pragma unroll
    for (int j = 0; j < 10; ++j)
        if (base + j < NN) out[base + j] = excl + loc[j];
    if (t == 1023) out[NN] = wtot[15];
}

// ---------------------------------------------------------------------------
// u_body: U_T[n][o][k] = f2bf(sum_i xin[n,i]*wb[k,i*32+o]); xb[n][o] likewise.
// vb in [0,2500): (16 nodes) x (8-of-32 o cols).
// ---------------------------------------------------------------------------
__device__ __forceinline__ void u_body(int vb, int tid, float* __restrict__ xs,
                                       const float* __restrict__ xin,
                                       const float* __restrict__ wbT,
                                       const float* __restrict__ bb,
                                       unsigned short* __restrict__ UT,
                                       float* __restrict__ xb) {
    const int nb = (vb >> 2) * 16;
    const int o0 = (vb & 3) * 8;
    for (int t = tid; t < 16 * C; t += 256) xs[t] = xin[nb * C + t];
    __syncthreads();

    const int op = tid >> 5, k = tid & 31, o = o0 + op;
    float4v wv[8];
    const float* wp = wbT + ((size_t)o * C + k) * C;
#pragma unroll
    for (int i4 = 0; i4 < 8; ++i4)
        wv[i4] = *reinterpret_cast<const float4v*>(wp + i4 * 4);

#pragma unroll
    for (int n = 0; n < 16; ++n) {
        float acc = 0.f;
#pragma unroll
        for (int i4 = 0; i4 < 8; ++i4) {
            const float4v xv = *reinterpret_cast<const float4v*>(&xs[n * C + i4 * 4]);
            acc += xv.x * wv[i4].x + xv.y * wv[i4].y + xv.z * wv[i4].z + xv.w * wv[i4].w;
        }
        UT[(size_t)(nb + n) * (C * C) + o * C + k] = f2bf(acc);
    }
    if (o0 == 0) {
#pragma unroll
        for (int t = 0; t < 2; ++t) {
            const int idx = t * 256 + tid;
            const int n = idx >> 5, oo = idx & 31;
            float acc = 0.f;
#pragma unroll
            for (int i = 0; i < C; ++i) acc += xs[n * C + i] * bb[i * C + oo];
            xb[(size_t)(nb + n) * C + oo] = acc;
        }
    }
}

// ---------------------------------------------------------------------------
// mid_kernel: blocks [0,625): scatter (CSR payload + dst-rank pd);
//             blocks [625,3125): u_body for conv1.
// ---------------------------------------------------------------------------
__global__ __launch_bounds__(256) void mid_kernel(const int* __restrict__ ei,
                                                  const float* __restrict__ ea,
                                                  const int* __restrict__ offs,
                                                  const int* __restrict__ doffs,
                                                  int* __restrict__ cur_src,
                                                  int* __restrict__ cur_dst,
                                                  int* __restrict__ pd,
                                                  float* __restrict__ ea_s,
                                                  const float* __restrict__ xin,
                                                  const float* __restrict__ wbT,
                                                  const float* __restrict__ bb,
                                                  unsigned short* __restrict__ UT,
                                                  float* __restrict__ xb) {
    __shared__ float xs[16 * C];
    const int b = blockIdx.x, tid = threadIdx.x;
    if (b < 625) {
        const int e = b * 256 + tid;
        if (e < NE) {
            const int sn  = ei[e];
            const int dn  = ei[NE + e];
            const int pos = offs[sn]  + atomicAdd(&cur_src[sn], 1);
            const int dpo = doffs[dn] + atomicAdd(&cur_dst[dn], 1);
            pd[pos] = dpo;
#pragma unroll
            for (int j = 0; j < ED; ++j)
                ea_s[(size_t)pos * EAP + j] = ea[(size_t)e * ED + j];
        }
    } else {
        u_body(b - 625, tid, xs, xin, wbT, bb, UT, xb);
    }
}

// u_gemm2 standalone (conv2, input h1)
__global__ __launch_bounds__(256) void u_gemm2(const float* __restrict__ xin,
                                               const float* __restrict__ wbT,
                                               const float* __restrict__ bb,
                                               unsigned short* __restrict__ UT,
                                               float* __restrict__ xb) {
    __shared__ float xs[16 * C];
    u_body(blockIdx.x, threadIdx.x, xs, xin, wbT, bb, UT, xb);
}

// ---------------------------------------------------------------------------
// edge5_kernel: one wave per src; 16-edge groups via MFMA; messages stored
// (no atomics) at dst-sorted rank pd[p]: msg[pd[p]][o].
// ---------------------------------------------------------------------------
__global__ __launch_bounds__(256) void edge5_kernel(const int* __restrict__ offs,
                                                    const int* __restrict__ pd,
                                                    const float* __restrict__ ea_s,
                                                    const float* __restrict__ wa,
                                                    const float* __restrict__ ba,
                                                    const unsigned short* __restrict__ UT,
                                                    const float* __restrict__ xb,
                                                    float* __restrict__ msg) {
    __shared__ float was[ED * C];
    __shared__ float bas[C];
    const int tid = threadIdx.x;
    for (int t = tid; t < ED * C; t += 256) was[t] = wa[t];
    if (tid < C) bas[tid] = ba[tid];
    __syncthreads();

    const int w  = tid >> 6;
    const int l  = tid & 63;
    const int s  = blockIdx.x * 4 + w;     // 2500*4 == 10000
    const int q  = l >> 4;                 // k-block 0..3
    const int el = l & 15;                 // edge row / output col

    const int e0 = offs[s], e1 = offs[s + 1];
    if (e0 == e1) return;

    const unsigned short* up = UT + (size_t)s * (C * C);
    const short8v B1 = *reinterpret_cast<const short8v*>(up + el * C + q * 8);
    const short8v B2 = *reinterpret_cast<const short8v*>(up + (el + 16) * C + q * 8);
    const float c1 = xb[s * C + el];
    const float c2 = xb[s * C + el + 16];
    const float4v C1 = {c1, c1, c1, c1};
    const float4v C2 = {c2, c2, c2, c2};
    float hb[8];
#pragma unroll
    for (int i = 0; i < 8; ++i) hb[i] = bas[q * 8 + i];

    for (int pb = e0; pb < e1; pb += 16) {
        const int p  = pb + el;
        const int pc = (p < e1) ? p : e0;          // clamp (masked at store)
        const float* eap = ea_s + (size_t)pc * EAP;
        const float4v ea0 = *reinterpret_cast<const float4v*>(eap);
        const float4v ea1 = *reinterpret_cast<const float4v*>(eap + 4);
        const float   ea8 = eap[8];

        float h[8];
#pragma unroll
        for (int i = 0; i < 8; ++i) h[i] = hb[i];
#pragma unroll
        for (int j = 0; j < ED; ++j) {
            const float ev = (j == 0) ? ea0.x : (j == 1) ? ea0.y : (j == 2) ? ea0.z
                           : (j == 3) ? ea0.w : (j == 4) ? ea1.x : (j == 5) ? ea1.y
                           : (j == 6) ? ea1.z : (j == 7) ? ea1.w : ea8;
            const float4v w0 = *reinterpret_cast<const float4v*>(&was[j * C + q * 8]);
            const float4v w1 = *reinterpret_cast<const float4v*>(&was[j * C + q * 8 + 4]);
            h[0] += ev * w0.x; h[1] += ev * w0.y; h[2] += ev * w0.z; h[3] += ev * w0.w;
            h[4] += ev * w1.x; h[5] += ev * w1.y; h[6] += ev * w1.z; h[7] += ev * w1.w;
        }
        union { int u[4]; short8v v; } A;
#pragma unroll
        for (int v = 0; v < 4; ++v) {
            const unsigned lo = f2bf(fmaxf(h[2 * v], 0.f));
            const unsigned hi = f2bf(fmaxf(h[2 * v + 1], 0.f));
            A.u[v] = (int)(lo | (hi << 16));
        }
        const float4v d1 = __builtin_amdgcn_mfma_f32_16x16x32_bf16(A.v, B1, C1, 0, 0, 0);
        const float4v d2 = __builtin_amdgcn_mfma_f32_16x16x32_bf16(A.v, B2, C2, 0, 0, 0);
#pragma unroll
        for (int r = 0; r < 4; ++r) {
            const int pe = pb + q * 4 + r;          // D row = (l>>4)*4 + r
            if (pe < e1) {
                const int mr = pd[pe];
                msg[(size_t)mr * C + el]      = d1[r];
                msg[(size_t)mr * C + el + 16] = d2[r];
            }
        }
    }
}

// ---------------------------------------------------------------------------
// nodeagg1: one wave per dst; segmented mean over msg rows + node update.
//   h1[d,o] = relu(mean + x[d,:]@root1[:,o] + bias1[o])
// ---------------------------------------------------------------------------
__global__ __launch_bounds__(256) void nodeagg1_kernel(const int* __restrict__ doffs,
                                                       const float* __restrict__ msg,
                                                       const float* __restrict__ xin,
                                                       const float* __restrict__ root,
                                                       const float* __restrict__ bias,
                                                       float* __restrict__ h1out) {
    __shared__ float rs[C * C];
    __shared__ float bs[C];
    __shared__ float xls[4][C];
    const int tid = threadIdx.x;
    for (int t = tid; t < C * C; t += 256) rs[t] = root[t];
    if (tid < C) bs[tid] = bias[tid];
    __syncthreads();

    const int w = tid >> 6, lane = tid & 63;
    const int half = lane >> 5, o = lane & 31;
    const int d = blockIdx.x * 4 + w;
    const int e0 = doffs[d], e1 = doffs[d + 1];

    float acc = 0.f;
    for (int p = e0 + half; p < e1; p += 2) acc += msg[(size_t)p * C + o];
    acc += __shfl_down(acc, 32, 64);                 // lanes 0-31 hold full sum
    if (lane < 32) xls[w][o] = xin[(size_t)d * C + o];  // wave-local, DS in-order
    if (lane < 32) {
        const float cn = fmaxf((float)(e1 - e0), 1.f);
        float a = bs[o] + acc / cn;
#pragma unroll
        for (int i = 0; i < C; ++i) a += xls[w][i] * rs[i * C + o];
        h1out[(size_t)d * C + o] = fmaxf(a, 0.f);
    }
}

// ---------------------------------------------------------------------------
// nodeagg2_score: one wave per dst; h2 in-register -> scores[d]. No fences.
// ---------------------------------------------------------------------------
__global__ __launch_bounds__(256) void nodeagg2_score(const int* __restrict__ doffs,
                                                      const float* __restrict__ msg,
                                                      const float* __restrict__ h1,
                                                      const float* __restrict__ root,
                                                      const float* __restrict__ bias,
                                                      const float* __restrict__ emb,
                                                      const int* __restrict__ signal,
                                                      float* __restrict__ scores) {
    __shared__ float rs[C * C];
    __shared__ float bs[C];
    __shared__ float sig[C];
    __shared__ float xls[4][C];
    const int tid = threadIdx.x;
    for (int t = tid; t < C * C; t += 256) rs[t] = root[t];
    if (tid < C) {
        bs[tid]  = bias[tid];
        sig[tid] = emb[(size_t)signal[0] * C + tid];
    }
    __syncthreads();

    const int w = tid >> 6, lane = tid & 63;
    const int half = lane >> 5, o = lane & 31;
    const int d = blockIdx.x * 4 + w;
    const int e0 = doffs[d], e1 = doffs[d + 1];

    float acc = 0.f;
    for (int p = e0 + half; p < e1; p += 2) acc += msg[(size_t)p * C + o];
    acc += __shfl_down(acc, 32, 64);
    if (lane < 32) xls[w][o] = h1[(size_t)d * C + o];
    if (lane < 32) {
        const float cn = fmaxf((float)(e1 - e0), 1.f);
        float a = bs[o] + acc / cn;
#pragma unroll
        for (int i = 0; i < C; ++i) a += xls[w][i] * rs[i * C + o];
        float val = fmaxf(a, 0.f) * sig[o];
#pragma unroll
        for (int off = 16; off; off >>= 1) val += __shfl_xor(val, off, 32);
        if (o == 0) scores[d] = val;
    }
}

// ---------------------------------------------------------------------------
// reduce_out_kernel: single block; logsumexp then writes the final output.
// ---------------------------------------------------------------------------
__global__ __launch_bounds__(1024) void reduce_out_kernel(const float* __restrict__ scores,
                                                          float* __restrict__ out) {
    __shared__ float sm[16];
    __shared__ float ss[16];
    const int tid = threadIdx.x;
    float m = -INFINITY;
    for (int n = tid; n < NN; n += 1024) m = fmaxf(m, scores[n]);
    for (int off = 32; off; off >>= 1) m = fmaxf(m, __shfl_down(m, off, 64));
    if ((tid & 63) == 0) sm[tid >> 6] = m;
    __syncthreads();
    if (tid == 0) {
        float mm = sm[0];
        for (int w = 1; w < 16; ++w) mm = fmaxf(mm, sm[w]);
        sm[0] = mm;
    }
    __syncthreads();
    const float gmax = sm[0];
    float s = 0.f;
    for (int n = tid; n < NN; n += 1024) s += expf(scores[n] - gmax);
    for (int off = 32; off; off >>= 1) s += __shfl_down(s, off, 64);
    if ((tid & 63) == 0) ss[tid >> 6] = s;
    __syncthreads();
    if (tid == 0) {
        float t = 0.f;
        for (int w = 0; w < 16; ++w) t += ss[w];
        ss[0] = logf(t);
    }
    __syncthreads();
    const float sub = gmax + ss[0];
    for (int n = tid; n < NN; n += 1024) out[n] = scores[n] - sub;
}

// ---------------------------------------------------------------------------
extern "C" void kernel_launch(void* const* d_in, const int* in_sizes, int n_in,
                              void* d_out, int out_size, void* d_ws, size_t ws_size,
                              hipStream_t stream) {
    const int*   signal = (const int*)d_in[0];
    const float* x      = (const float*)d_in[1];
    const int*   ei     = (const int*)d_in[2];
    const float* ea     = (const float*)d_in[3];
    const float* w1a    = (const float*)d_in[4];
    const float* b1a    = (const float*)d_in[5];
    const float* w1b    = (const float*)d_in[6];
    const float* b1b    = (const float*)d_in[7];
    const float* root1  = (const float*)d_in[8];
    const float* bias1  = (const float*)d_in[9];
    const float* w2a    = (const float*)d_in[10];
    const float* b2a    = (const float*)d_in[11];
    const float* w2b    = (const float*)d_in[12];
    const float* b2b    = (const float*)d_in[13];
    const float* root2  = (const float*)d_in[14];
    const float* bias2  = (const float*)d_in[15];
    const float* emb    = (const float*)d_in[16];

    // ---- workspace layout (float words; ws_size = 256 MiB, we use ~52 MB) ----
    float* ws = (float*)d_ws;
    unsigned short* UT = (unsigned short*)ws;         // 5,120,000 words (20.5 MB)
    float* msg     = ws + 5120000;                    // 5,120,000 (20.5 MB)
    float* xb      = msg + 5120000;                   // 320,000
    float* h1      = xb + 320000;                     // 320,000
    float* ea_s    = h1 + 320000;                     // 1,920,000
    float* wbT1    = ea_s + 1920000;                  // 32,768
    float* wbT2    = wbT1 + 32768;                    // 32,768
    float* scores  = wbT2 + 32768;                    // 10,000
    int*   offs    = (int*)(scores + 10000);          // 10,016
    int*   doffs   = offs + 10016;                    // 10,016
    int*   pd      = doffs + 10016;                   // 160,000
    // ---- zero region (40,064 ints == 10,016 uint4, zeroed by prep) ----
    int*   cnt_src = pd + 160000;                     // 10,000
    int*   cnt_dst = cnt_src + NN;                    // 10,000
    int*   cur_src = cnt_dst + NN;                    // 10,000
    int*   cur_dst = cur_src + NN;                    // 10,000 (+64 pad)

    // 1: zero + both wb transposes
    prep_kernel<<<296, 256, 0, stream>>>((uint4*)cnt_src, w1b, w2b, wbT1, wbT2);
    // 2: degree histograms
    hist_kernel<<<(NE + 255) / 256, 256, 0, stream>>>(ei, cnt_src, cnt_dst);
    // 3: both prefix scans
    scan2_kernel<<<2, 1024, 0, stream>>>(cnt_src, cnt_dst, offs, doffs);
    // 4: scatter (CSR payload + dst ranks)  ||  conv1 U/xb
    mid_kernel<<<3125, 256, 0, stream>>>(ei, ea, offs, doffs, cur_src, cur_dst,
                                         pd, ea_s, x, wbT1, b1b, UT, xb);
    // 5: conv1 edge MFMA -> msg (dst-sorted, no atomics)
    edge5_kernel<<<2500, 256, 0, stream>>>(offs, pd, ea_s, w1a, b1a, UT, xb, msg);
    // 6: conv1 segmented mean + node update -> h1
    nodeagg1_kernel<<<2500, 256, 0, stream>>>(doffs, msg, x, root1, bias1, h1);
    // 7: conv2 U/xb from h1
    u_gemm2<<<2500, 256, 0, stream>>>(h1, wbT2, b2b, UT, xb);
    // 8: conv2 edge MFMA -> msg
    edge5_kernel<<<2500, 256, 0, stream>>>(offs, pd, ea_s, w2a, b2a, UT, xb, msg);
    // 9: conv2 aggregation + score (no fences)
    nodeagg2_score<<<2500, 256, 0, stream>>>(doffs, msg, h1, root2, bias2,
                                             emb, signal, scores);
    // 10: logsumexp + output
    reduce_out_kernel<<<1, 1024, 0, stream>>>(scores, (float*)d_out);
}

// Round 9
// 143.844 us; speedup vs baseline: 2.3688x; 1.0919x over previous
//
#include <hip/hip_runtime.h>
#include <math.h>

#define NN 10000      // nodes
#define NE 160000     // edges
#define C  32         // FEAT == EMB == HID == 32
#define ED 9          // edge feature dim
#define EAP 12        // padded edge-attr stride (16B-aligned float4 loads)

typedef __attribute__((ext_vector_type(8))) short short8v;   // 8 bf16 (4 VGPR)
typedef __attribute__((ext_vector_type(4))) float float4v;

__device__ inline unsigned short f2bf(float f) {        // fp32 -> bf16 RNE
    unsigned int u = __float_as_uint(f);
    return (unsigned short)((u + 0x7fffu + ((u >> 16) & 1u)) >> 16);
}
__device__ inline float bf2f(unsigned int us) { return __uint_as_float(us << 16); }

// ---------------------------------------------------------------------------
// prep_kernel: blocks [0,40) zero the atomic region (cnt/cursors);
//              [40,168) build wbB1; [168,296) build wbB2.
// wbB[j*32+i] = bf16(wb[(j&31)*1024 + i*32 + (j>>5)])   (j = o*32+k_out)
// ---------------------------------------------------------------------------
#define ZQ 10016      // uint4s in zero region (40064 ints)
__global__ __launch_bounds__(256) void prep_kernel(uint4* __restrict__ zreg,
                                                   const float* __restrict__ w1b,
                                                   const float* __restrict__ w2b,
                                                   unsigned short* __restrict__ wbB1,
                                                   unsigned short* __restrict__ wbB2) {
    const int b = blockIdx.x, tid = threadIdx.x;
    if (b < 40) {
        const int i = b * 256 + tid;
        if (i < ZQ) zreg[i] = uint4{0u, 0u, 0u, 0u};
    } else if (b < 168) {
        const int idx = (b - 40) * 256 + tid;             // 0..32767
        const int i = idx & 31, j = idx >> 5;
        wbB1[idx] = f2bf(w1b[(j & 31) * (C * C) + i * C + (j >> 5)]);
    } else {
        const int idx = (b - 168) * 256 + tid;
        const int i = idx & 31, j = idx >> 5;
        wbB2[idx] = f2bf(w2b[(j & 31) * (C * C) + i * C + (j >> 5)]);
    }
}

// ---------------------------------------------------------------------------
// hist_kernel: out-degree (src) and in-degree (dst) histograms
// ---------------------------------------------------------------------------
__global__ __launch_bounds__(256) void hist_kernel(const int* __restrict__ ei,
                                                   int* __restrict__ cnt_src,
                                                   int* __restrict__ cnt_dst) {
    const int e = blockIdx.x * 256 + threadIdx.x;
    if (e < NE) {
        atomicAdd(&cnt_src[ei[e]], 1);
        atomicAdd(&cnt_dst[ei[NE + e]], 1);
    }
}

// ---------------------------------------------------------------------------
// scan2_kernel: block 0: offs = exscan(cnt_src); block 1: doffs = exscan(cnt_dst)
// ---------------------------------------------------------------------------
__global__ __launch_bounds__(1024) void scan2_kernel(const int* __restrict__ cnt_src,
                                                     const int* __restrict__ cnt_dst,
                                                     int* __restrict__ offs,
                                                     int* __restrict__ doffs) {
    const int* cnt = blockIdx.x ? cnt_dst : cnt_src;
    int* out       = blockIdx.x ? doffs   : offs;
    __shared__ int wtot[16];
    const int t = threadIdx.x;
    const int lane = t & 63, wid = t >> 6;
    const int base = t * 10;
    int loc[10];
    int s = 0;
#pragma unroll
    for (int j = 0; j < 10; ++j) {
        int v = (base + j < NN) ? cnt[base + j] : 0;
        loc[j] = s;
        s += v;
    }
    int inc = s;
    for (int d = 1; d < 64; d <<= 1) {
        int v = __shfl_up(inc, d, 64);
        if (lane >= d) inc += v;
    }
    if (lane == 63) wtot[wid] = inc;
    __syncthreads();
    if (t < 16) {
        int w = wtot[t];
        for (int d = 1; d < 16; d <<= 1) {
            int v = __shfl_up(w, d, 64);
            if (t >= d) w += v;
        }
        wtot[t] = w;
    }
    __syncthreads();
    const int excl = inc - s + (wid ? wtot[wid - 1] : 0);
#pragma unroll
    for (int j = 0; j < 10; ++j)
        if (base + j < NN) out[base + j] = excl + loc[j];
    if (t == 1023) out[NN] = wtot[15];
}

// ---------------------------------------------------------------------------
// u_mfma_body: U_T[n][j] = bf16(sum_i xin[n,i] * wbB_src[j][i]) via MFMA with
// x hi/lo bf16 split (error ~= single wb rounding). Also xb[n][o] (fp32 VALU).
// vb in [0,625): 16 nodes each, 4 waves x 16 j-tiles of 16.
//   A-frag: wbB[(jbase + (l&15))*32 + (l>>4)*8 ..+8]   (16B L2 load)
//   B-frag: x_bf16[node=l&15][k=(l>>4)*8 ..+8]         (16B LDS load)
//   D: col=node=l&15, row=j_local=(l>>4)*4+r -> one 8B store per tile
// ---------------------------------------------------------------------------
__device__ __forceinline__ void u_mfma_body(int vb, int tid,
                                            float* __restrict__ xs,
                                            unsigned int* __restrict__ bhi,
                                            unsigned int* __restrict__ blo,
                                            const float* __restrict__ xin,
                                            const unsigned short* __restrict__ wbB,
                                            const float* __restrict__ bb,
                                            unsigned short* __restrict__ UT,
                                            float* __restrict__ xb) {
    const int nb = vb * 16;
    {   // stage x: fp32 (for xb) + packed bf16 hi/lo (for MFMA B-frags)
        const float2 v = *reinterpret_cast<const float2*>(xin + nb * C + 2 * tid);
        xs[2 * tid] = v.x; xs[2 * tid + 1] = v.y;
        const unsigned hx = f2bf(v.x), hy = f2bf(v.y);
        bhi[tid] = hx | (hy << 16);
        const float lx = v.x - bf2f(hx), ly = v.y - bf2f(hy);
        blo[tid] = (unsigned)f2bf(lx) | ((unsigned)f2bf(ly) << 16);
    }
    __syncthreads();

    const int w = tid >> 6, l = tid & 63;
    const int r15 = l & 15, q = l >> 4;
    const short8v Bh = *reinterpret_cast<const short8v*>(
        reinterpret_cast<const unsigned short*>(bhi) + r15 * C + q * 8);
    const short8v Bl = *reinterpret_cast<const short8v*>(
        reinterpret_cast<const unsigned short*>(blo) + r15 * C + q * 8);
    const float4v Z = {0.f, 0.f, 0.f, 0.f};

#pragma unroll
    for (int cg = 0; cg < 4; ++cg) {
        const int jbase = w * 256 + cg * 64 + 0;   // process 4 j-tiles per cg iter
#pragma unroll
        for (int t4 = 0; t4 < 4; ++t4) {
            const int jb = jbase + t4 * 16;
            const short8v A = *reinterpret_cast<const short8v*>(
                wbB + (size_t)(jb + r15) * C + q * 8);
            float4v acc = __builtin_amdgcn_mfma_f32_16x16x32_bf16(A, Bl, Z, 0, 0, 0);
            acc = __builtin_amdgcn_mfma_f32_16x16x32_bf16(A, Bh, acc, 0, 0, 0);
            ushort4 pk;
            pk.x = f2bf(acc[0]); pk.y = f2bf(acc[1]);
            pk.z = f2bf(acc[2]); pk.w = f2bf(acc[3]);
            *reinterpret_cast<ushort4*>(UT + (size_t)(nb + r15) * (C * C) + jb + q * 4) = pk;
        }
    }
    // xb tile: 512 outputs, 2 per thread (fp32)
#pragma unroll
    for (int t = 0; t < 2; ++t) {
        const int idx = t * 256 + tid;
        const int n = idx >> 5, oo = idx & 31;
        float acc = 0.f;
#pragma unroll
        for (int i = 0; i < C; ++i) acc += xs[n * C + i] * bb[i * C + oo];
        xb[(size_t)(nb + n) * C + oo] = acc;
    }
}

// ---------------------------------------------------------------------------
// mid_kernel: blocks [0,625): scatter (CSR payload + dst-rank pd);
//             blocks [625,1250): u_mfma_body for conv1.
// ---------------------------------------------------------------------------
__global__ __launch_bounds__(256) void mid_kernel(const int* __restrict__ ei,
                                                  const float* __restrict__ ea,
                                                  const int* __restrict__ offs,
                                                  const int* __restrict__ doffs,
                                                  int* __restrict__ cur_src,
                                                  int* __restrict__ cur_dst,
                                                  int* __restrict__ pd,
                                                  float* __restrict__ ea_s,
                                                  const float* __restrict__ xin,
                                                  const unsigned short* __restrict__ wbB,
                                                  const float* __restrict__ bb,
                                                  unsigned short* __restrict__ UT,
                                                  float* __restrict__ xb) {
    __shared__ float xs[16 * C];
    __shared__ unsigned int bhi[256], blo[256];
    const int b = blockIdx.x, tid = threadIdx.x;
    if (b < 625) {
        const int e = b * 256 + tid;
        if (e < NE) {
            const int sn  = ei[e];
            const int dn  = ei[NE + e];
            const int pos = offs[sn]  + atomicAdd(&cur_src[sn], 1);
            const int dpo = doffs[dn] + atomicAdd(&cur_dst[dn], 1);
            pd[pos] = dpo;
#pragma unroll
            for (int j = 0; j < ED; ++j)
                ea_s[(size_t)pos * EAP + j] = ea[(size_t)e * ED + j];
        }
    } else {
        u_mfma_body(b - 625, tid, xs, bhi, blo, xin, wbB, bb, UT, xb);
    }
}

// u_mfma standalone (conv2, input h1)
__global__ __launch_bounds__(256) void u_mfma(const float* __restrict__ xin,
                                              const unsigned short* __restrict__ wbB,
                                              const float* __restrict__ bb,
                                              unsigned short* __restrict__ UT,
                                              float* __restrict__ xb) {
    __shared__ float xs[16 * C];
    __shared__ unsigned int bhi[256], blo[256];
    u_mfma_body(blockIdx.x, threadIdx.x, xs, bhi, blo, xin, wbB, bb, UT, xb);
}

// ---------------------------------------------------------------------------
// edge5_kernel: one wave per src; 16-edge groups via MFMA; messages stored
// (no atomics) at dst-sorted rank pd[p]: msg[pd[p]][o].
// ---------------------------------------------------------------------------
__global__ __launch_bounds__(256) void edge5_kernel(const int* __restrict__ offs,
                                                    const int* __restrict__ pd,
                                                    const float* __restrict__ ea_s,
                                                    const float* __restrict__ wa,
                                                    const float* __restrict__ ba,
                                                    const unsigned short* __restrict__ UT,
                                                    const float* __restrict__ xb,
                                                    float* __restrict__ msg) {
    __shared__ float was[ED * C];
    __shared__ float bas[C];
    const int tid = threadIdx.x;
    for (int t = tid; t < ED * C; t += 256) was[t] = wa[t];
    if (tid < C) bas[tid] = ba[tid];
    __syncthreads();

    const int w  = tid >> 6;
    const int l  = tid & 63;
    const int s  = blockIdx.x * 4 + w;     // 2500*4 == 10000
    const int q  = l >> 4;                 // k-block 0..3
    const int el = l & 15;                 // edge row / output col

    const int e0 = offs[s], e1 = offs[s + 1];
    if (e0 == e1) return;

    const unsigned short* up = UT + (size_t)s * (C * C);
    const short8v B1 = *reinterpret_cast<const short8v*>(up + el * C + q * 8);
    const short8v B2 = *reinterpret_cast<const short8v*>(up + (el + 16) * C + q * 8);
    const float c1 = xb[s * C + el];
    const float c2 = xb[s * C + el + 16];
    const float4v C1 = {c1, c1, c1, c1};
    const float4v C2 = {c2, c2, c2, c2};
    float hb[8];
#pragma unroll
    for (int i = 0; i < 8; ++i) hb[i] = bas[q * 8 + i];

    for (int pb = e0; pb < e1; pb += 16) {
        const int p  = pb + el;
        const int pc = (p < e1) ? p : e0;          // clamp (masked at store)
        const float* eap = ea_s + (size_t)pc * EAP;
        const float4v ea0 = *reinterpret_cast<const float4v*>(eap);
        const float4v ea1 = *reinterpret_cast<const float4v*>(eap + 4);
        const float   ea8 = eap[8];

        float h[8];
#pragma unroll
        for (int i = 0; i < 8; ++i) h[i] = hb[i];
#pragma unroll
        for (int j = 0; j < ED; ++j) {
            const float ev = (j == 0) ? ea0.x : (j == 1) ? ea0.y : (j == 2) ? ea0.z
                           : (j == 3) ? ea0.w : (j == 4) ? ea1.x : (j == 5) ? ea1.y
                           : (j == 6) ? ea1.z : (j == 7) ? ea1.w : ea8;
            const float4v w0 = *reinterpret_cast<const float4v*>(&was[j * C + q * 8]);
            const float4v w1 = *reinterpret_cast<const float4v*>(&was[j * C + q * 8 + 4]);
            h[0] += ev * w0.x; h[1] += ev * w0.y; h[2] += ev * w0.z; h[3] += ev * w0.w;
            h[4] += ev * w1.x; h[5] += ev * w1.y; h[6] += ev * w1.z; h[7] += ev * w1.w;
        }
        union { int u[4]; short8v v; } A;
#pragma unroll
        for (int v = 0; v < 4; ++v) {
            const unsigned lo = f2bf(fmaxf(h[2 * v], 0.f));
            const unsigned hi = f2bf(fmaxf(h[2 * v + 1], 0.f));
            A.u[v] = (int)(lo | (hi << 16));
        }
        const float4v d1 = __builtin_amdgcn_mfma_f32_16x16x32_bf16(A.v, B1, C1, 0, 0, 0);
        const float4v d2 = __builtin_amdgcn_mfma_f32_16x16x32_bf16(A.v, B2, C2, 0, 0, 0);
#pragma unroll
        for (int r = 0; r < 4; ++r) {
            const int pe = pb + q * 4 + r;          // D row = (l>>4)*4 + r
            if (pe < e1) {
                const int mr = pd[pe];
                msg[(size_t)mr * C + el]      = d1[r];
                msg[(size_t)mr * C + el + 16] = d2[r];
            }
        }
    }
}

// ---------------------------------------------------------------------------
// nodeagg1: one wave per dst; segmented mean over msg rows + node update.
// ---------------------------------------------------------------------------
__global__ __launch_bounds__(256) void nodeagg1_kernel(const int* __restrict__ doffs,
                                                       const float* __restrict__ msg,
                                                       const float* __restrict__ xin,
                                                       const float* __restrict__ root,
                                                       const float* __restrict__ bias,
                                                       float* __restrict__ h1out) {
    __shared__ float rs[C * C];
    __shared__ float bs[C];
    __shared__ float xls[4][C];
    const int tid = threadIdx.x;
    for (int t = tid; t < C * C; t += 256) rs[t] = root[t];
    if (tid < C) bs[tid] = bias[tid];
    __syncthreads();

    const int w = tid >> 6, lane = tid & 63;
    const int half = lane >> 5, o = lane & 31;
    const int d = blockIdx.x * 4 + w;
    const int e0 = doffs[d], e1 = doffs[d + 1];

    float acc = 0.f;
    for (int p = e0 + half; p < e1; p += 2) acc += msg[(size_t)p * C + o];
    acc += __shfl_down(acc, 32, 64);                 // lanes 0-31 hold full sum
    if (lane < 32) xls[w][o] = xin[(size_t)d * C + o];  // wave-local, DS in-order
    if (lane < 32) {
        const float cn = fmaxf((float)(e1 - e0), 1.f);
        float a = bs[o] + acc / cn;
#pragma unroll
        for (int i = 0; i < C; ++i) a += xls[w][i] * rs[i * C + o];
        h1out[(size_t)d * C + o] = fmaxf(a, 0.f);
    }
}

// ---------------------------------------------------------------------------
// nodeagg2_score: one wave per dst; h2 in-register -> scores[d]. No fences.
// ---------------------------------------------------------------------------
__global__ __launch_bounds__(256) void nodeagg2_score(const int* __restrict__ doffs,
                                                      const float* __restrict__ msg,
                                                      const float* __restrict__ h1,
                                                      const float* __restrict__ root,
                                                      const float* __restrict__ bias,
                                                      const float* __restrict__ emb,
                                                      const int* __restrict__ signal,
                                                      float* __restrict__ scores) {
    __shared__ float rs[C * C];
    __shared__ float bs[C];
    __shared__ float sig[C];
    __shared__ float xls[4][C];
    const int tid = threadIdx.x;
    for (int t = tid; t < C * C; t += 256) rs[t] = root[t];
    if (tid < C) {
        bs[tid]  = bias[tid];
        sig[tid] = emb[(size_t)signal[0] * C + tid];
    }
    __syncthreads();

    const int w = tid >> 6, lane = tid & 63;
    const int half = lane >> 5, o = lane & 31;
    const int d = blockIdx.x * 4 + w;
    const int e0 = doffs[d], e1 = doffs[d + 1];

    float acc = 0.f;
    for (int p = e0 + half; p < e1; p += 2) acc += msg[(size_t)p * C + o];
    acc += __shfl_down(acc, 32, 64);
    if (lane < 32) xls[w][o] = h1[(size_t)d * C + o];
    if (lane < 32) {
        const float cn = fmaxf((float)(e1 - e0), 1.f);
        float a = bs[o] + acc / cn;
#pragma unroll
        for (int i = 0; i < C; ++i) a += xls[w][i] * rs[i * C + o];
        float val = fmaxf(a, 0.f) * sig[o];
#pragma unroll
        for (int off = 16; off; off >>= 1) val += __shfl_xor(val, off, 32);
        if (o == 0) scores[d] = val;
    }
}

// ---------------------------------------------------------------------------
// reduce_out_kernel: single block; logsumexp then writes the final output.
// ---------------------------------------------------------------------------
__global__ __launch_bounds__(1024) void reduce_out_kernel(const float* __restrict__ scores,
                                                          float* __restrict__ out) {
    __shared__ float sm[16];
    __shared__ float ss[16];
    const int tid = threadIdx.x;
    float m = -INFINITY;
    for (int n = tid; n < NN; n += 1024) m = fmaxf(m, scores[n]);
    for (int off = 32; off; off >>= 1) m = fmaxf(m, __shfl_down(m, off, 64));
    if ((tid & 63) == 0) sm[tid >> 6] = m;
    __syncthreads();
    if (tid == 0) {
        float mm = sm[0];
        for (int w = 1; w < 16; ++w) mm = fmaxf(mm, sm[w]);
        sm[0] = mm;
    }
    __syncthreads();
    const float gmax = sm[0];
    float s = 0.f;
    for (int n = tid; n < NN; n += 1024) s += expf(scores[n] - gmax);
    for (int off = 32; off; off >>= 1) s += __shfl_down(s, off, 64);
    if ((tid & 63) == 0) ss[tid >> 6] = s;
    __syncthreads();
    if (tid == 0) {
        float t = 0.f;
        for (int w = 0; w < 16; ++w) t += ss[w];
        ss[0] = logf(t);
    }
    __syncthreads();
    const float sub = gmax + ss[0];
    for (int n = tid; n < NN; n += 1024) out[n] = scores[n] - sub;
}

// ---------------------------------------------------------------------------
extern "C" void kernel_launch(void* const* d_in, const int* in_sizes, int n_in,
                              void* d_out, int out_size, void* d_ws, size_t ws_size,
                              hipStream_t stream) {
    const int*   signal = (const int*)d_in[0];
    const float* x      = (const float*)d_in[1];
    const int*   ei     = (const int*)d_in[2];
    const float* ea     = (const float*)d_in[3];
    const float* w1a    = (const float*)d_in[4];
    const float* b1a    = (const float*)d_in[5];
    const float* w1b    = (const float*)d_in[6];
    const float* b1b    = (const float*)d_in[7];
    const float* root1  = (const float*)d_in[8];
    const float* bias1  = (const float*)d_in[9];
    const float* w2a    = (const float*)d_in[10];
    const float* b2a    = (const float*)d_in[11];
    const float* w2b    = (const float*)d_in[12];
    const float* b2b    = (const float*)d_in[13];
    const float* root2  = (const float*)d_in[14];
    const float* bias2  = (const float*)d_in[15];
    const float* emb    = (const float*)d_in[16];

    // ---- workspace layout (float words) ----
    float* ws = (float*)d_ws;
    unsigned short* UT = (unsigned short*)ws;         // 5,120,000 words (20.5 MB)
    float* msg     = ws + 5120000;                    // 5,120,000 (20.5 MB)
    float* xb      = msg + 5120000;                   // 320,000
    float* h1      = xb + 320000;                     // 320,000
    float* ea_s    = h1 + 320000;                     // 1,920,000
    unsigned short* wbB1 = (unsigned short*)(ea_s + 1920000);  // 32768 ushorts
    unsigned short* wbB2 = wbB1 + 32768;              // 32768 ushorts
    float* scores  = ea_s + 1920000 + 32768;          // 10,000 (after 2x16384 words)
    int*   offs    = (int*)(scores + 10000);          // 10,016
    int*   doffs   = offs + 10016;                    // 10,016
    int*   pd      = doffs + 10016;                   // 160,000
    // ---- zero region (40,064 ints == 10,016 uint4, zeroed by prep) ----
    int*   cnt_src = pd + 160000;                     // 10,000
    int*   cnt_dst = cnt_src + NN;                    // 10,000
    int*   cur_src = cnt_dst + NN;                    // 10,000
    int*   cur_dst = cur_src + NN;                    // 10,000 (+64 pad)

    // 1: zero + both wbB tables
    prep_kernel<<<296, 256, 0, stream>>>((uint4*)cnt_src, w1b, w2b, wbB1, wbB2);
    // 2: degree histograms
    hist_kernel<<<(NE + 255) / 256, 256, 0, stream>>>(ei, cnt_src, cnt_dst);
    // 3: both prefix scans
    scan2_kernel<<<2, 1024, 0, stream>>>(cnt_src, cnt_dst, offs, doffs);
    // 4: scatter (CSR payload + dst ranks)  ||  conv1 U/xb via MFMA
    mid_kernel<<<1250, 256, 0, stream>>>(ei, ea, offs, doffs, cur_src, cur_dst,
                                         pd, ea_s, x, wbB1, b1b, UT, xb);
    // 5: conv1 edge MFMA -> msg (dst-sorted, no atomics)
    edge5_kernel<<<2500, 256, 0, stream>>>(offs, pd, ea_s, w1a, b1a, UT, xb, msg);
    // 6: conv1 segmented mean + node update -> h1
    nodeagg1_kernel<<<2500, 256, 0, stream>>>(doffs, msg, x, root1, bias1, h1);
    // 7: conv2 U/xb from h1 via MFMA
    u_mfma<<<625, 256, 0, stream>>>(h1, wbB2, b2b, UT, xb);
    // 8: conv2 edge MFMA -> msg
    edge5_kernel<<<2500, 256, 0, stream>>>(offs, pd, ea_s, w2a, b2a, UT, xb, msg);
    // 9: conv2 aggregation + score (no fences)
    nodeagg2_score<<<2500, 256, 0, stream>>>(doffs, msg, h1, root2, bias2,
                                             emb, signal, scores);
    // 10: logsumexp + output
    reduce_out_kernel<<<1, 1024, 0, stream>>>(scores, (float*)d_out);
}